// Round 5
// baseline (145055.408 us; speedup 1.0000x reference)
//
#include <hip/hip_runtime.h>
#include <hip/hip_bf16.h>
#include <stdint.h>

// WindowAttention: B_=256 windows, N=98 tokens, DIM=768, NH=24, HD=32.
// Round 5: fp32-VALU anchor + FP32 OUTPUT + in_sizes-based input binding.
// One block per (window b, head h). Head h uses contiguous qkv_w rows
// [h*96,(h+1)*96): channel c = h*96 + d*3 + s, s in {q,k,v}.

#define NTOK 98
#define DIMX 768
#define NHEAD 24
#define HDIM 32
#define SCALE 0.17677669529663689f

__device__ __forceinline__ float ldf(const void* p, size_t i, int bf) {
    return bf ? (float)((const __hip_bfloat16*)p)[i] : ((const float*)p)[i];
}

// Classify input[0]: bf16-packed or fp32 (bits14..7 of dwords: bf16 data has
// exponent there, in [100,140] w.p. ~0.999; fp32 mantissa bits ~0.16).
__global__ void detect_kernel(const uint32_t* __restrict__ xw, int* __restrict__ flag) {
    __shared__ int cnts[256];
    int t = threadIdx.x, c = 0;
    for (int i = t; i < 4096; i += 256) {
        uint32_t e = (xw[i] >> 7) & 0xFFu;
        c += (e >= 100u && e <= 140u) ? 1 : 0;
    }
    cnts[t] = c;
    __syncthreads();
    for (int s = 128; s > 0; s >>= 1) {
        if (t < s) cnts[t] += cnts[t + s];
        __syncthreads();
    }
    if (t == 0) flag[0] = (cnts[0] > 2048) ? 1 : 0;
}

struct __align__(16) SMem {
    union {
        struct {
            float xs[NTOK][33];   // 12936 B
            float ws[96][33];     // 12672 B
        } p1;
        float S[NTOK][99];        // 38808 B (scores, then probs in place)
    } u;
    float q[NTOK][33];            // 12936 B
    float k[NTOK][33];            // 12936 B
    float v[NTOK][33];            // 12936 B
};                                // 77616 B -> 2 blocks/CU

__global__ __launch_bounds__(256, 2) void attn_kernel(
    const void* __restrict__ x,
    const void* __restrict__ mask,
    const void* __restrict__ qkv_w,
    const void* __restrict__ qkv_b,
    const void* __restrict__ rel_table,
    const int* __restrict__ rel_index,
    const int* __restrict__ flag,      // null -> fp32
    float* __restrict__ out)
{
    __shared__ SMem sm;
    const int bf  = flag ? flag[0] : 0;
    const int tid = threadIdx.x;
    const int b = blockIdx.x / NHEAD;
    const int h = blockIdx.x % NHEAD;
    const size_t xoff = (size_t)b * NTOK * DIMX;
    const size_t woff = (size_t)h * 96 * DIMX;

    // ---------- Phase 1: qkv(98x96) = x(98x768) @ w^T, BK=32 chunks ----------
    float acc[37];
    #pragma unroll
    for (int i = 0; i < 37; ++i) acc[i] = 0.f;

    for (int kb = 0; kb < 24; ++kb) {
        for (int t = tid; t < NTOK * 32; t += 256) {
            int row = t >> 5, c = t & 31;
            sm.u.p1.xs[row][c] = ldf(x, xoff + (size_t)row * DIMX + kb * 32 + c, bf);
        }
        for (int t = tid; t < 96 * 32; t += 256) {
            int row = t >> 5, c = t & 31;
            sm.u.p1.ws[row][c] = ldf(qkv_w, woff + (size_t)row * DIMX + kb * 32 + c, bf);
        }
        __syncthreads();
        #pragma unroll
        for (int i = 0; i < 37; ++i) {
            int o = tid + i * 256;
            if (o < NTOK * 96) {
                int t = o / 96, col = o % 96;
                float s = 0.f;
                #pragma unroll
                for (int c = 0; c < 32; ++c)
                    s += sm.u.p1.xs[t][c] * sm.u.p1.ws[col][c];
                acc[i] += s;
            }
        }
        __syncthreads();
    }

    // Epilogue: de-interleave into q[t][d], k[t][d], v[t][d] (+bias)
    #pragma unroll
    for (int i = 0; i < 37; ++i) {
        int o = tid + i * 256;
        if (o < NTOK * 96) {
            int t = o / 96, col = o % 96;
            int d = col / 3, s = col % 3;
            float val = acc[i] + ldf(qkv_b, (size_t)h * 96 + col, bf);
            if (s == 0)      sm.q[t][d] = val;
            else if (s == 1) sm.k[t][d] = val;
            else             sm.v[t][d] = val;
        }
    }
    __syncthreads();

    // ---------- Phase 2: S = q k^T * SCALE + bias + mask ----------
    const size_t moff = (size_t)(b & 63) * NTOK * NTOK;
    #pragma unroll
    for (int i = 0; i < 38; ++i) {
        int o = tid + i * 256;
        if (o < NTOK * NTOK) {
            int qi = o / NTOK, kj = o % NTOK;
            float s = 0.f;
            #pragma unroll
            for (int c = 0; c < HDIM; ++c)
                s += sm.q[qi][c] * sm.k[kj][c];
            float bias = ldf(rel_table, (size_t)rel_index[o] * NHEAD + h, bf);
            sm.u.S[qi][kj] = s * SCALE + bias + ldf(mask, moff + o, bf);
        }
    }
    __syncthreads();

    // ---------- Softmax (thread i owns row i) ----------
    if (tid < NTOK) {
        float mx = -1e30f;
        for (int j = 0; j < NTOK; ++j) mx = fmaxf(mx, sm.u.S[tid][j]);
        float sum = 0.f;
        for (int j = 0; j < NTOK; ++j) sum += __expf(sm.u.S[tid][j] - mx);
        float inv = 1.f / sum;
        for (int j = 0; j < NTOK; ++j)
            sm.u.S[tid][j] = __expf(sm.u.S[tid][j] - mx) * inv;
    }
    __syncthreads();

    // ---------- Phase 3: O = P(98x98) @ V(98x32), FP32 out ----------
    float* ob = out + (size_t)b * NTOK * DIMX + h * HDIM;
    #pragma unroll
    for (int i = 0; i < 13; ++i) {
        int o = tid + i * 256;
        if (o < NTOK * HDIM) {
            int t = o / HDIM, d = o % HDIM;
            float s = 0.f;
            for (int j = 0; j < NTOK; ++j)
                s += sm.u.S[t][j] * sm.v[j][d];
            ob[(size_t)t * DIMX + d] = s;
        }
    }
}

extern "C" void kernel_launch(void* const* d_in, const int* in_sizes, int n_in,
                              void* d_out, int out_size, void* d_ws, size_t ws_size,
                              hipStream_t stream) {
    // Bind inputs by their unique element counts (robust to ordering).
    const void* x = d_in[0];  const void* mask = d_in[1];
    const void* qkv_w = d_in[2]; const void* qkv_b = d_in[3];
    const void* rel_table = d_in[4]; const int* rel_index = (const int*)d_in[5];
    for (int i = 0; i < n_in; ++i) {
        switch (in_sizes[i]) {
            case 256 * NTOK * DIMX:      x         = d_in[i]; break; // 19267584
            case 64 * NTOK * NTOK:       mask      = d_in[i]; break; // 614656
            case 3 * DIMX * DIMX:        qkv_w     = d_in[i]; break; // 1769472
            case 3 * DIMX:               qkv_b     = d_in[i]; break; // 2304
            case 507 * NHEAD:            rel_table = d_in[i]; break; // 12168
            case NTOK * NTOK:            rel_index = (const int*)d_in[i]; break; // 9604
            default: break;
        }
    }
    float* out = (float*)d_out;

    int* flagp = (ws_size >= 16) ? (int*)d_ws : nullptr;
    if (flagp)
        detect_kernel<<<1, 256, 0, stream>>>((const uint32_t*)x, flagp);
    attn_kernel<<<256 * NHEAD, 256, 0, stream>>>(x, mask, qkv_w, qkv_b,
                                                 rel_table, rel_index, flagp, out);
}

// Round 6
// 917.630 us; speedup vs baseline: 158.0761x; 158.0761x over previous
//
#include <hip/hip_runtime.h>
#include <hip/hip_bf16.h>
#include <stdint.h>

// WindowAttention: B_=256 windows, N=98 tokens, DIM=768, NH=24, HD=32.
// Round 6: MFMA kernel (round-3 structure) + FP32 OUTPUT (proven in round 5)
// + in_sizes input binding. One block per (window b, head h); head h uses
// contiguous qkv_w rows [h*96,(h+1)*96): channel c = h*96 + d*3 + s.

#define NTOK 98
#define MT 7
#define NPAD 112
#define DIMX 768
#define NHEAD 24
#define HDIM 32
#define SCALE 0.17677669529663689f

typedef __attribute__((ext_vector_type(8))) short short8;
typedef __attribute__((ext_vector_type(4))) short short4v;
typedef __attribute__((ext_vector_type(4))) float floatx4;

__device__ __forceinline__ short f2b(float f) {
    __hip_bfloat16 h = __float2bfloat16(f);
    return __builtin_bit_cast(short, h);
}
__device__ __forceinline__ float ldf(const void* p, size_t i, int bf) {
    return bf ? (float)((const __hip_bfloat16*)p)[i] : ((const float*)p)[i];
}

// Classify input x: bf16-packed or fp32 (bits14..7 of dwords: bf16 data has
// exponent there, in [100,140] w.p. ~0.999; fp32 mantissa bits ~0.16).
__global__ void detect_kernel(const uint32_t* __restrict__ xw, int* __restrict__ flag) {
    __shared__ int cnts[256];
    int t = threadIdx.x, c = 0;
    for (int i = t; i < 4096; i += 256) {
        uint32_t e = (xw[i] >> 7) & 0xFFu;
        c += (e >= 100u && e <= 140u) ? 1 : 0;
    }
    cnts[t] = c;
    __syncthreads();
    for (int s = 128; s > 0; s >>= 1) {
        if (t < s) cnts[t] += cnts[t + s];
        __syncthreads();
    }
    if (t == 0) flag[0] = (cnts[0] > 2048) ? 1 : 0;
}

// bias_pre[h][i][j] = rel_table[rel_index[i][j]][h]
__global__ void bias_gather_kernel(const void* __restrict__ rel_table,
                                   const int* __restrict__ rel_index,
                                   const int* __restrict__ flag,
                                   float* __restrict__ bias_pre) {
    int t = blockIdx.x * 256 + threadIdx.x;
    if (t >= NHEAD * NTOK * NTOK) return;
    int bf = flag[0];
    int h  = t / (NTOK * NTOK);
    int ij = t % (NTOK * NTOK);
    bias_pre[t] = ldf(rel_table, (size_t)rel_index[ij] * NHEAD + h, bf);
}

struct __align__(16) SMem {
    union {
        struct {
            short xt[NPAD * 64];   // 14336 B (rows >= 98 zeroed each step)
            short wt[96 * 64];     // 12288 B
        } p1;
        short P[NPAD * 128];       // 28672 B (bf16 probs; cols>=112 zeroed)
    } u;                           // 28672 B
    short q[NPAD * HDIM];          // 7168 B  [tok][d]
    short k[NPAD * HDIM];          // 7168 B  [tok][d]
    short vt[HDIM * 128];          // 8192 B  [d][tok], cols >= 98 zeroed
};                                 // 51200 B -> 3 blocks/CU

__global__ __launch_bounds__(256, 3) void attn_kernel(
    const void* __restrict__ x,
    const void* __restrict__ mask,
    const void* __restrict__ qkv_w,
    const void* __restrict__ qkv_b,
    const float* __restrict__ bias_pre,     // may be null -> inline gather
    const void* __restrict__ rel_table,
    const int* __restrict__ rel_index,
    const int* __restrict__ flag,           // may be null -> fp32
    float* __restrict__ out)
{
    __shared__ SMem sm;
    const int bf   = flag ? flag[0] : 0;
    const int tid  = threadIdx.x;
    const int lane = tid & 63;
    const int wv   = tid >> 6;
    const int l15  = lane & 15;
    const int l4   = lane >> 4;

    const int b = blockIdx.x / NHEAD;
    const int h = blockIdx.x % NHEAD;

    const size_t xoff = (size_t)b * NTOK * DIMX;
    const size_t woff = (size_t)h * 96 * DIMX;

    int mt[2];
    mt[0] = wv;
    mt[1] = (wv + 4 < MT) ? (wv + 4) : wv;   // wave3 duplicates tile 3 (benign)

    const floatx4 zero4 = {0.f, 0.f, 0.f, 0.f};

    // ---------------- Phase 1: qkv(98x96) = x(98x768) @ w^T ----------------
    floatx4 acc[2][6];
    #pragma unroll
    for (int i = 0; i < 2; ++i)
        #pragma unroll
        for (int j = 0; j < 6; ++j) acc[i][j] = zero4;

    for (int kb = 0; kb < 12; ++kb) {         // BK = 64
        if (bf) {
            const uint16_t* xp = (const uint16_t*)x + xoff;
            const uint16_t* wp = (const uint16_t*)qkv_w + woff;
            for (int t = tid; t < NTOK * 8; t += 256) {
                int row = t >> 3, c = t & 7;
                *(uint4*)(&sm.u.p1.xt[row * 64 + c * 8]) =
                    *(const uint4*)(xp + (size_t)row * DIMX + kb * 64 + c * 8);
            }
            for (int t = tid; t < 96 * 8; t += 256) {
                int row = t >> 3, c = t & 7;
                *(uint4*)(&sm.u.p1.wt[row * 64 + c * 8]) =
                    *(const uint4*)(wp + (size_t)row * DIMX + kb * 64 + c * 8);
            }
        } else {
            const float* xp = (const float*)x + xoff;
            const float* wp = (const float*)qkv_w + woff;
            for (int t = tid; t < NTOK * 16; t += 256) {
                int row = t >> 4, c = t & 15;
                float4 f = *(const float4*)(xp + (size_t)row * DIMX + kb * 64 + c * 4);
                short4v s = { f2b(f.x), f2b(f.y), f2b(f.z), f2b(f.w) };
                *(short4v*)(&sm.u.p1.xt[row * 64 + c * 4]) = s;
            }
            for (int t = tid; t < 96 * 16; t += 256) {
                int row = t >> 4, c = t & 15;
                float4 f = *(const float4*)(wp + (size_t)row * DIMX + kb * 64 + c * 4);
                short4v s = { f2b(f.x), f2b(f.y), f2b(f.z), f2b(f.w) };
                *(short4v*)(&sm.u.p1.wt[row * 64 + c * 4]) = s;
            }
        }
        // zero xt pad rows 98..111
        if (tid < 14 * 8) {
            int row = 98 + (tid >> 3), c = tid & 7;
            uint4 z = {0u, 0u, 0u, 0u};
            *(uint4*)(&sm.u.p1.xt[row * 64 + c * 8]) = z;
        }
        __syncthreads();
        #pragma unroll
        for (int ks = 0; ks < 2; ++ks) {
            int k0 = ks * 32 + l4 * 8;
            short8 aM[2];
            #pragma unroll
            for (int im = 0; im < 2; ++im)
                aM[im] = *(const short8*)(&sm.u.p1.xt[(mt[im] * 16 + l15) * 64 + k0]);
            #pragma unroll
            for (int nt = 0; nt < 6; ++nt) {
                short8 bN = *(const short8*)(&sm.u.p1.wt[(nt * 16 + l15) * 64 + k0]);
                #pragma unroll
                for (int im = 0; im < 2; ++im)
                    acc[im][nt] = __builtin_amdgcn_mfma_f32_16x16x32_bf16(
                        aM[im], bN, acc[im][nt], 0, 0, 0);
            }
        }
        __syncthreads();
    }

    // Epilogue: de-interleave into q[tok][d], k[tok][d], vt[d][tok] (+bias)
    #pragma unroll
    for (int im = 0; im < 2; ++im) {
        #pragma unroll
        for (int nt = 0; nt < 6; ++nt) {
            int col = nt * 16 + l15;          // d*3 + s
            int d = col / 3, s = col % 3;
            float bias = ldf(qkv_b, (size_t)h * 96 + col, bf);
            #pragma unroll
            for (int r = 0; r < 4; ++r) {
                int tok = mt[im] * 16 + l4 * 4 + r;
                short val = f2b(acc[im][nt][r] + bias);
                if (s == 0)      sm.q[tok * HDIM + d] = val;
                else if (s == 1) sm.k[tok * HDIM + d] = val;
                else             sm.vt[d * 128 + tok] = val;
            }
        }
    }
    __syncthreads();
    // zero vt cols 98..127 and P cols 112..127 (softmax stores cover <=111)
    for (int t = tid; t < HDIM * 30; t += 256) {
        int d = t / 30, c = 98 + t % 30;
        sm.vt[d * 128 + c] = 0;
    }
    for (int t = tid; t < NPAD * 16; t += 256) {
        int row = t >> 4, c = 112 + (t & 15);
        sm.u.P[row * 128 + c] = 0;
    }

    // ---------------- Phase 2: S = q @ k^T, in-register softmax ------------
    floatx4 sacc[2][7];
    #pragma unroll
    for (int i = 0; i < 2; ++i)
        #pragma unroll
        for (int j = 0; j < 7; ++j) sacc[i][j] = zero4;
    {
        int k0 = l4 * 8;
        short8 aq[2];
        #pragma unroll
        for (int im = 0; im < 2; ++im)
            aq[im] = *(const short8*)(&sm.q[(mt[im] * 16 + l15) * HDIM + k0]);
        #pragma unroll
        for (int nt = 0; nt < 7; ++nt) {
            short8 bk = *(const short8*)(&sm.k[(nt * 16 + l15) * HDIM + k0]);
            #pragma unroll
            for (int im = 0; im < 2; ++im)
                sacc[im][nt] = __builtin_amdgcn_mfma_f32_16x16x32_bf16(
                    aq[im], bk, sacc[im][nt], 0, 0, 0);
        }
    }

    const float* biash = bias_pre ? (bias_pre + (size_t)h * NTOK * NTOK) : nullptr;
    const size_t moff = (size_t)(b & 63) * NTOK * NTOK;

    #pragma unroll
    for (int im = 0; im < 2; ++im) {
        #pragma unroll
        for (int r = 0; r < 4; ++r) {
            int row = mt[im] * 16 + l4 * 4 + r;
            bool vrow = row < NTOK;
            float v[7];
            #pragma unroll
            for (int nt = 0; nt < 7; ++nt) {
                int j = nt * 16 + l15;
                bool vj = vrow && (j < NTOK);
                float bm = 0.f;
                if (vj) {
                    float bias = biash ? biash[row * NTOK + j]
                        : ldf(rel_table, (size_t)rel_index[row * NTOK + j] * NHEAD + h, bf);
                    bm = bias + ldf(mask, moff + row * NTOK + j, bf);
                }
                v[nt] = vj ? sacc[im][nt][r] * SCALE + bm : -1e30f;
            }
            float mx = v[0];
            #pragma unroll
            for (int nt = 1; nt < 7; ++nt) mx = fmaxf(mx, v[nt]);
            #pragma unroll
            for (int off = 1; off < 16; off <<= 1) mx = fmaxf(mx, __shfl_xor(mx, off));
            float s = 0.f;
            #pragma unroll
            for (int nt = 0; nt < 7; ++nt) {
                float e = (v[nt] > -1e29f) ? __expf(v[nt] - mx) : 0.f;
                v[nt] = e;
                s += e;
            }
            #pragma unroll
            for (int off = 1; off < 16; off <<= 1) s += __shfl_xor(s, off);
            float inv = vrow ? 1.f / s : 0.f;   // rows >= 98 -> zero probs
            #pragma unroll
            for (int nt = 0; nt < 7; ++nt)
                sm.u.P[row * 128 + nt * 16 + l15] = f2b(v[nt] * inv);
        }
    }
    __syncthreads();

    // ---------------- Phase 3: O = P(98x128pad) @ V(128x32) ----------------
    floatx4 oacc[2][2];
    #pragma unroll
    for (int i = 0; i < 2; ++i)
        #pragma unroll
        for (int j = 0; j < 2; ++j) oacc[i][j] = zero4;

    #pragma unroll
    for (int kt = 0; kt < 4; ++kt) {
        int kk = kt * 32 + l4 * 8;
        short8 ap[2];
        #pragma unroll
        for (int im = 0; im < 2; ++im)
            ap[im] = *(const short8*)(&sm.u.P[(mt[im] * 16 + l15) * 128 + kk]);
        #pragma unroll
        for (int nt = 0; nt < 2; ++nt) {
            short8 bv = *(const short8*)(&sm.vt[(nt * 16 + l15) * 128 + kk]);
            #pragma unroll
            for (int im = 0; im < 2; ++im)
                oacc[im][nt] = __builtin_amdgcn_mfma_f32_16x16x32_bf16(
                    ap[im], bv, oacc[im][nt], 0, 0, 0);
        }
    }

    float* ob = out + (size_t)b * NTOK * DIMX + h * HDIM;   // FP32 output
    #pragma unroll
    for (int im = 0; im < 2; ++im)
        #pragma unroll
        for (int nt = 0; nt < 2; ++nt) {
            int dd = nt * 16 + l15;
            #pragma unroll
            for (int r = 0; r < 4; ++r) {
                int tok = mt[im] * 16 + l4 * 4 + r;
                if (tok < NTOK)
                    ob[(size_t)tok * DIMX + dd] = oacc[im][nt][r];
            }
        }
}

extern "C" void kernel_launch(void* const* d_in, const int* in_sizes, int n_in,
                              void* d_out, int out_size, void* d_ws, size_t ws_size,
                              hipStream_t stream) {
    // Bind inputs by their unique element counts (robust to ordering).
    const void* x = d_in[0];  const void* mask = d_in[1];
    const void* qkv_w = d_in[2]; const void* qkv_b = d_in[3];
    const void* rel_table = d_in[4]; const int* rel_index = (const int*)d_in[5];
    for (int i = 0; i < n_in; ++i) {
        switch (in_sizes[i]) {
            case 256 * NTOK * DIMX:  x         = d_in[i]; break; // 19267584
            case 64 * NTOK * NTOK:   mask      = d_in[i]; break; // 614656
            case 3 * DIMX * DIMX:    qkv_w     = d_in[i]; break; // 1769472
            case 3 * DIMX:           qkv_b     = d_in[i]; break; // 2304
            case 507 * NHEAD:        rel_table = d_in[i]; break; // 12168
            case NTOK * NTOK:        rel_index = (const int*)d_in[i]; break; // 9604
            default: break;
        }
    }
    float* out = (float*)d_out;

    int* flagp = (ws_size >= 16) ? (int*)d_ws : nullptr;
    const size_t bias_bytes = (size_t)NHEAD * NTOK * NTOK * sizeof(float);
    float* bias_pre = (flagp && ws_size >= 16 + bias_bytes)
                      ? (float*)((char*)d_ws + 16) : nullptr;

    if (flagp)
        detect_kernel<<<1, 256, 0, stream>>>((const uint32_t*)x, flagp);
    if (bias_pre) {
        int n = NHEAD * NTOK * NTOK;
        bias_gather_kernel<<<(n + 255) / 256, 256, 0, stream>>>(rel_table, rel_index,
                                                                flagp, bias_pre);
    }
    attn_kernel<<<256 * NHEAD, 256, 0, stream>>>(x, mask, qkv_w, qkv_b,
                                                 bias_pre, rel_table, rel_index,
                                                 flagp, out);
}

// Round 7
// 483.373 us; speedup vs baseline: 300.0900x; 1.8984x over previous
//
#include <hip/hip_runtime.h>
#include <hip/hip_bf16.h>
#include <stdint.h>

// WindowAttention: B_=256 windows, N=98 tokens, DIM=768, NH=24, HD=32.
// Round 7: pipeline — convert(x,W)->bf16, m97-style MFMA GEMM for qkv,
// then per-(window,head) attention. Falls back to the round-6 fused kernel
// if ws_size is too small. Inputs fp32, output fp32 (proven round 5/6).

#define NTOK 98
#define MT 7
#define NPAD 112
#define DIMX 768
#define NHEAD 24
#define HDIM 32
#define NQKV 2304          // 3*DIM
#define BROWS 25088        // 256*98
#define SCALE 0.17677669529663689f

typedef __attribute__((ext_vector_type(8))) short short8;
typedef __attribute__((ext_vector_type(4))) short short4v;
typedef __attribute__((ext_vector_type(4))) float floatx4;

__device__ __forceinline__ short f2b(float f) {
    __hip_bfloat16 h = __float2bfloat16(f);
    return __builtin_bit_cast(short, h);
}

__device__ __forceinline__ void gload_lds16(const void* g, void* l) {
    __builtin_amdgcn_global_load_lds(
        (const __attribute__((address_space(1))) void*)g,
        (__attribute__((address_space(3))) void*)l, 16, 0, 0);
}

// ---------------- fp32 -> bf16 bulk convert ----------------
__global__ void convert_kernel(const float* __restrict__ src,
                               short* __restrict__ dst, int n4) {
    int i = blockIdx.x * 256 + threadIdx.x;
    int stride = gridDim.x * 256;
    for (; i < n4; i += stride) {
        float4 f = ((const float4*)src)[i];
        short4v s = { f2b(f.x), f2b(f.y), f2b(f.z), f2b(f.w) };
        ((short4v*)dst)[i] = s;
    }
}

// bias_pre[h][i][j] = rel_table[rel_index[i][j]][h]
__global__ void bias_gather_kernel(const float* __restrict__ rel_table,
                                   const int* __restrict__ rel_index,
                                   float* __restrict__ bias_pre) {
    int t = blockIdx.x * 256 + threadIdx.x;
    if (t >= NHEAD * NTOK * NTOK) return;
    int h  = t / (NTOK * NTOK);
    int ij = t % (NTOK * NTOK);
    bias_pre[t] = rel_table[(size_t)rel_index[ij] * NHEAD + h];
}

// ---------------- GEMM: qkv[25088][2304] = xb @ wb^T + qkv_b ----------------
// 128x128 tiles, BK=64, 256 thr (2x2 waves, each 4x4 16x16 MFMA tiles).
__global__ void gemm_kernel(const short* __restrict__ xb,
                            const short* __restrict__ wb,
                            const float* __restrict__ qkv_b,
                            short* __restrict__ qkv) {
    __shared__ short At[128 * 64];
    __shared__ short Bt[128 * 64];
    const int tid  = threadIdx.x;
    const int lane = tid & 63;
    const int wv   = tid >> 6;
    const int wr   = wv >> 1, wc = wv & 1;
    const int l15  = lane & 15;
    const int l4   = lane >> 4;

    const int mtile = blockIdx.x / 18;
    const int ntile = blockIdx.x % 18;

    const short* aB = xb + (size_t)(mtile * 128) * DIMX;
    const short* bB = wb + (size_t)(ntile * 128) * DIMX;
    const int lrow = lane >> 3;         // 0..7
    const int lcol = (lane & 7) * 8;    // 0..56

    floatx4 acc[4][4];
    #pragma unroll
    for (int m = 0; m < 4; ++m)
        #pragma unroll
        for (int n = 0; n < 4; ++n) acc[m][n] = (floatx4){0.f, 0.f, 0.f, 0.f};

    for (int kb = 0; kb < 12; ++kb) {
        #pragma unroll
        for (int j = 0; j < 4; ++j) {
            int r = wv * 32 + j * 8;
            gload_lds16(aB + (size_t)(r + lrow) * DIMX + kb * 64 + lcol, &At[r * 64]);
            gload_lds16(bB + (size_t)(r + lrow) * DIMX + kb * 64 + lcol, &Bt[r * 64]);
        }
        __syncthreads();
        #pragma unroll
        for (int kh = 0; kh < 2; ++kh) {
            int k0 = kh * 32 + l4 * 8;
            short8 af[4], bfr[4];
            #pragma unroll
            for (int m = 0; m < 4; ++m)
                af[m] = *(const short8*)(&At[(wr * 64 + m * 16 + l15) * 64 + k0]);
            #pragma unroll
            for (int n = 0; n < 4; ++n)
                bfr[n] = *(const short8*)(&Bt[(wc * 64 + n * 16 + l15) * 64 + k0]);
            #pragma unroll
            for (int m = 0; m < 4; ++m)
                #pragma unroll
                for (int n = 0; n < 4; ++n)
                    acc[m][n] = __builtin_amdgcn_mfma_f32_16x16x32_bf16(
                        af[m], bfr[n], acc[m][n], 0, 0, 0);
        }
        __syncthreads();
    }

    #pragma unroll
    for (int n = 0; n < 4; ++n) {
        int col = ntile * 128 + wc * 64 + n * 16 + l15;
        float bias = qkv_b[col];
        #pragma unroll
        for (int m = 0; m < 4; ++m) {
            int row0 = mtile * 128 + wr * 64 + m * 16 + l4 * 4;
            #pragma unroll
            for (int r = 0; r < 4; ++r)
                qkv[(size_t)(row0 + r) * NQKV + col] = f2b(acc[m][n][r] + bias);
        }
    }
}

// ---------------- Attention per (window b, head h) ----------------
struct __align__(16) SMemB {
    short P[NPAD * 128];   // 28672 B (bf16 probs; cols >= 112 zeroed)
    short q[NPAD * HDIM];  // 7168 B  [tok][d]
    short k[NPAD * HDIM];  // 7168 B  [tok][d]
    short vt[HDIM * 128];  // 8192 B  [d][tok], cols >= 98 zeroed
};                         // 51200 B -> 3 blocks/CU

__global__ __launch_bounds__(256, 3) void attn_kernel2(
    const short* __restrict__ qkv,
    const float* __restrict__ mask,
    const float* __restrict__ bias_pre,
    float* __restrict__ out) {
    __shared__ SMemB sm;
    const int tid  = threadIdx.x;
    const int lane = tid & 63;
    const int wv   = tid >> 6;
    const int l15  = lane & 15;
    const int l4   = lane >> 4;
    const int b = blockIdx.x / NHEAD;
    const int h = blockIdx.x % NHEAD;

    // Stage qkv slice: rows b*98..+97, cols h*96..+95; de-interleave.
    for (int idx = tid; idx < NTOK * 12; idx += 256) {
        int t = idx / 12, g = idx % 12;
        short8 v = *(const short8*)(qkv + (size_t)(b * NTOK + t) * NQKV + h * 96 + g * 8);
        #pragma unroll
        for (int cc = 0; cc < 8; ++cc) {
            int c = g * 8 + cc;
            int d = c / 3, s = c % 3;
            short val = v[cc];
            if (s == 0)      sm.q[t * HDIM + d] = val;
            else if (s == 1) sm.k[t * HDIM + d] = val;
            else             sm.vt[d * 128 + t] = val;
        }
    }
    // zero pads: q/k rows 98..111, vt cols 98..127, P cols 112..127
    for (int t = tid; t < 14 * HDIM; t += 256) {
        int row = 98 + t / HDIM, d = t % HDIM;
        sm.q[row * HDIM + d] = 0;
        sm.k[row * HDIM + d] = 0;
    }
    for (int t = tid; t < HDIM * 30; t += 256) {
        int d = t / 30, c = 98 + t % 30;
        sm.vt[d * 128 + c] = 0;
    }
    for (int t = tid; t < NPAD * 16; t += 256) {
        int row = t >> 4, c = 112 + (t & 15);
        sm.P[row * 128 + c] = 0;
    }
    __syncthreads();

    int mt[2];
    mt[0] = wv;
    mt[1] = (wv + 4 < MT) ? (wv + 4) : wv;

    // Phase 2: S = q @ k^T (K=32, one MFMA step)
    floatx4 sacc[2][7];
    #pragma unroll
    for (int i = 0; i < 2; ++i)
        #pragma unroll
        for (int j = 0; j < 7; ++j) sacc[i][j] = (floatx4){0.f, 0.f, 0.f, 0.f};
    {
        int k0 = l4 * 8;
        short8 aq[2];
        #pragma unroll
        for (int im = 0; im < 2; ++im)
            aq[im] = *(const short8*)(&sm.q[(mt[im] * 16 + l15) * HDIM + k0]);
        #pragma unroll
        for (int nt = 0; nt < 7; ++nt) {
            short8 bk = *(const short8*)(&sm.k[(nt * 16 + l15) * HDIM + k0]);
            #pragma unroll
            for (int im = 0; im < 2; ++im)
                sacc[im][nt] = __builtin_amdgcn_mfma_f32_16x16x32_bf16(
                    aq[im], bk, sacc[im][nt], 0, 0, 0);
        }
    }

    const float* biash = bias_pre + (size_t)h * NTOK * NTOK;
    const size_t moff = (size_t)(b & 63) * NTOK * NTOK;

    #pragma unroll
    for (int im = 0; im < 2; ++im) {
        #pragma unroll
        for (int r = 0; r < 4; ++r) {
            int row = mt[im] * 16 + l4 * 4 + r;
            bool vrow = row < NTOK;
            float v[7];
            #pragma unroll
            for (int nt = 0; nt < 7; ++nt) {
                int j = nt * 16 + l15;
                bool vj = vrow && (j < NTOK);
                float bm = 0.f;
                if (vj) bm = biash[row * NTOK + j] + mask[moff + row * NTOK + j];
                v[nt] = vj ? sacc[im][nt][r] * SCALE + bm : -1e30f;
            }
            float mx = v[0];
            #pragma unroll
            for (int nt = 1; nt < 7; ++nt) mx = fmaxf(mx, v[nt]);
            #pragma unroll
            for (int off = 1; off < 16; off <<= 1) mx = fmaxf(mx, __shfl_xor(mx, off));
            float s = 0.f;
            #pragma unroll
            for (int nt = 0; nt < 7; ++nt) {
                float e = (v[nt] > -1e29f) ? __expf(v[nt] - mx) : 0.f;
                v[nt] = e;
                s += e;
            }
            #pragma unroll
            for (int off = 1; off < 16; off <<= 1) s += __shfl_xor(s, off);
            float inv = vrow ? 1.f / s : 0.f;
            #pragma unroll
            for (int nt = 0; nt < 7; ++nt)
                sm.P[row * 128 + nt * 16 + l15] = f2b(v[nt] * inv);
        }
    }
    __syncthreads();

    // Phase 3: O = P(98x128pad) @ V(128x32)
    floatx4 oacc[2][2];
    #pragma unroll
    for (int i = 0; i < 2; ++i)
        #pragma unroll
        for (int j = 0; j < 2; ++j) oacc[i][j] = (floatx4){0.f, 0.f, 0.f, 0.f};

    #pragma unroll
    for (int kt = 0; kt < 4; ++kt) {
        int kk = kt * 32 + l4 * 8;
        short8 ap[2];
        #pragma unroll
        for (int im = 0; im < 2; ++im)
            ap[im] = *(const short8*)(&sm.P[(mt[im] * 16 + l15) * 128 + kk]);
        #pragma unroll
        for (int nt = 0; nt < 2; ++nt) {
            short8 bv = *(const short8*)(&sm.vt[(nt * 16 + l15) * 128 + kk]);
            #pragma unroll
            for (int im = 0; im < 2; ++im)
                oacc[im][nt] = __builtin_amdgcn_mfma_f32_16x16x32_bf16(
                    ap[im], bv, oacc[im][nt], 0, 0, 0);
        }
    }

    float* ob = out + (size_t)b * NTOK * DIMX + h * HDIM;
    #pragma unroll
    for (int im = 0; im < 2; ++im)
        #pragma unroll
        for (int nt = 0; nt < 2; ++nt) {
            int dd = nt * 16 + l15;
            #pragma unroll
            for (int r = 0; r < 4; ++r) {
                int tok = mt[im] * 16 + l4 * 4 + r;
                if (tok < NTOK)
                    ob[(size_t)tok * DIMX + dd] = oacc[im][nt][r];
            }
        }
}

// ---------------- Fallback: round-6 fused kernel (fp32 in, fp32 out) -------
struct __align__(16) SMemF {
    union {
        struct {
            short xt[NPAD * 64];
            short wt[96 * 64];
        } p1;
        short P[NPAD * 128];
    } u;
    short q[NPAD * HDIM];
    short k[NPAD * HDIM];
    short vt[HDIM * 128];
};

__global__ __launch_bounds__(256, 3) void attn_fused(
    const float* __restrict__ x,
    const float* __restrict__ mask,
    const float* __restrict__ qkv_w,
    const float* __restrict__ qkv_b,
    const float* __restrict__ bias_pre,
    const float* __restrict__ rel_table,
    const int* __restrict__ rel_index,
    float* __restrict__ out) {
    __shared__ SMemF sm;
    const int tid  = threadIdx.x;
    const int lane = tid & 63;
    const int wv   = tid >> 6;
    const int l15  = lane & 15;
    const int l4   = lane >> 4;
    const int b = blockIdx.x / NHEAD;
    const int h = blockIdx.x % NHEAD;
    const float* xp = x + (size_t)b * NTOK * DIMX;
    const float* wp = qkv_w + (size_t)h * 96 * DIMX;
    int mt[2];
    mt[0] = wv;
    mt[1] = (wv + 4 < MT) ? (wv + 4) : wv;

    floatx4 acc[2][6];
    #pragma unroll
    for (int i = 0; i < 2; ++i)
        #pragma unroll
        for (int j = 0; j < 6; ++j) acc[i][j] = (floatx4){0.f, 0.f, 0.f, 0.f};

    for (int kb = 0; kb < 12; ++kb) {
        for (int t = tid; t < NTOK * 16; t += 256) {
            int row = t >> 4, c = t & 15;
            float4 f = *(const float4*)(xp + (size_t)row * DIMX + kb * 64 + c * 4);
            short4v s = { f2b(f.x), f2b(f.y), f2b(f.z), f2b(f.w) };
            *(short4v*)(&sm.u.p1.xt[row * 64 + c * 4]) = s;
        }
        for (int t = tid; t < 96 * 16; t += 256) {
            int row = t >> 4, c = t & 15;
            float4 f = *(const float4*)(wp + (size_t)row * DIMX + kb * 64 + c * 4);
            short4v s = { f2b(f.x), f2b(f.y), f2b(f.z), f2b(f.w) };
            *(short4v*)(&sm.u.p1.wt[row * 64 + c * 4]) = s;
        }
        if (tid < 14 * 8) {
            int row = 98 + (tid >> 3), c = tid & 7;
            uint4 z = {0u, 0u, 0u, 0u};
            *(uint4*)(&sm.u.p1.xt[row * 64 + c * 8]) = z;
        }
        __syncthreads();
        #pragma unroll
        for (int ks = 0; ks < 2; ++ks) {
            int k0 = ks * 32 + l4 * 8;
            short8 aM[2];
            #pragma unroll
            for (int im = 0; im < 2; ++im)
                aM[im] = *(const short8*)(&sm.u.p1.xt[(mt[im] * 16 + l15) * 64 + k0]);
            #pragma unroll
            for (int nt = 0; nt < 6; ++nt) {
                short8 bN = *(const short8*)(&sm.u.p1.wt[(nt * 16 + l15) * 64 + k0]);
                #pragma unroll
                for (int im = 0; im < 2; ++im)
                    acc[im][nt] = __builtin_amdgcn_mfma_f32_16x16x32_bf16(
                        aM[im], bN, acc[im][nt], 0, 0, 0);
            }
        }
        __syncthreads();
    }

    #pragma unroll
    for (int im = 0; im < 2; ++im)
        #pragma unroll
        for (int nt = 0; nt < 6; ++nt) {
            int col = nt * 16 + l15;
            int d = col / 3, s = col % 3;
            float bias = qkv_b[h * 96 + col];
            #pragma unroll
            for (int r = 0; r < 4; ++r) {
                int tok = mt[im] * 16 + l4 * 4 + r;
                short val = f2b(acc[im][nt][r] + bias);
                if (s == 0)      sm.q[tok * HDIM + d] = val;
                else if (s == 1) sm.k[tok * HDIM + d] = val;
                else             sm.vt[d * 128 + tok] = val;
            }
        }
    __syncthreads();
    for (int t = tid; t < HDIM * 30; t += 256) {
        int d = t / 30, c = 98 + t % 30;
        sm.vt[d * 128 + c] = 0;
    }
    for (int t = tid; t < NPAD * 16; t += 256) {
        int row = t >> 4, c = 112 + (t & 15);
        sm.u.P[row * 128 + c] = 0;
    }

    floatx4 sacc[2][7];
    #pragma unroll
    for (int i = 0; i < 2; ++i)
        #pragma unroll
        for (int j = 0; j < 7; ++j) sacc[i][j] = (floatx4){0.f, 0.f, 0.f, 0.f};
    {
        int k0 = l4 * 8;
        short8 aq[2];
        #pragma unroll
        for (int im = 0; im < 2; ++im)
            aq[im] = *(const short8*)(&sm.q[(mt[im] * 16 + l15) * HDIM + k0]);
        #pragma unroll
        for (int nt = 0; nt < 7; ++nt) {
            short8 bk = *(const short8*)(&sm.k[(nt * 16 + l15) * HDIM + k0]);
            #pragma unroll
            for (int im = 0; im < 2; ++im)
                sacc[im][nt] = __builtin_amdgcn_mfma_f32_16x16x32_bf16(
                    aq[im], bk, sacc[im][nt], 0, 0, 0);
        }
    }

    const float* biash = bias_pre ? (bias_pre + (size_t)h * NTOK * NTOK) : nullptr;
    const size_t moff = (size_t)(b & 63) * NTOK * NTOK;

    #pragma unroll
    for (int im = 0; im < 2; ++im)
        #pragma unroll
        for (int r = 0; r < 4; ++r) {
            int row = mt[im] * 16 + l4 * 4 + r;
            bool vrow = row < NTOK;
            float v[7];
            #pragma unroll
            for (int nt = 0; nt < 7; ++nt) {
                int j = nt * 16 + l15;
                bool vj = vrow && (j < NTOK);
                float bm = 0.f;
                if (vj) {
                    float bias = biash ? biash[row * NTOK + j]
                        : rel_table[(size_t)rel_index[row * NTOK + j] * NHEAD + h];
                    bm = bias + mask[moff + row * NTOK + j];
                }
                v[nt] = vj ? sacc[im][nt][r] * SCALE + bm : -1e30f;
            }
            float mx = v[0];
            #pragma unroll
            for (int nt = 1; nt < 7; ++nt) mx = fmaxf(mx, v[nt]);
            #pragma unroll
            for (int off = 1; off < 16; off <<= 1) mx = fmaxf(mx, __shfl_xor(mx, off));
            float s = 0.f;
            #pragma unroll
            for (int nt = 0; nt < 7; ++nt) {
                float e = (v[nt] > -1e29f) ? __expf(v[nt] - mx) : 0.f;
                v[nt] = e;
                s += e;
            }
            #pragma unroll
            for (int off = 1; off < 16; off <<= 1) s += __shfl_xor(s, off);
            float inv = vrow ? 1.f / s : 0.f;
            #pragma unroll
            for (int nt = 0; nt < 7; ++nt)
                sm.u.P[row * 128 + nt * 16 + l15] = f2b(v[nt] * inv);
        }
    __syncthreads();

    floatx4 oacc[2][2];
    #pragma unroll
    for (int i = 0; i < 2; ++i)
        #pragma unroll
        for (int j = 0; j < 2; ++j) oacc[i][j] = (floatx4){0.f, 0.f, 0.f, 0.f};
    #pragma unroll
    for (int kt = 0; kt < 4; ++kt) {
        int kk = kt * 32 + l4 * 8;
        short8 ap[2];
        #pragma unroll
        for (int im = 0; im < 2; ++im)
            ap[im] = *(const short8*)(&sm.u.P[(mt[im] * 16 + l15) * 128 + kk]);
        #pragma unroll
        for (int nt = 0; nt < 2; ++nt) {
            short8 bv = *(const short8*)(&sm.vt[(nt * 16 + l15) * 128 + kk]);
            #pragma unroll
            for (int im = 0; im < 2; ++im)
                oacc[im][nt] = __builtin_amdgcn_mfma_f32_16x16x32_bf16(
                    ap[im], bv, oacc[im][nt], 0, 0, 0);
        }
    }
    float* ob = out + (size_t)b * NTOK * DIMX + h * HDIM;
    #pragma unroll
    for (int im = 0; im < 2; ++im)
        #pragma unroll
        for (int nt = 0; nt < 2; ++nt) {
            int dd = nt * 16 + l15;
            #pragma unroll
            for (int r = 0; r < 4; ++r) {
                int tok = mt[im] * 16 + l4 * 4 + r;
                if (tok < NTOK)
                    ob[(size_t)tok * DIMX + dd] = oacc[im][nt][r];
            }
        }
}

extern "C" void kernel_launch(void* const* d_in, const int* in_sizes, int n_in,
                              void* d_out, int out_size, void* d_ws, size_t ws_size,
                              hipStream_t stream) {
    const float* x = (const float*)d_in[0];
    const float* mask = (const float*)d_in[1];
    const float* qkv_w = (const float*)d_in[2];
    const float* qkv_b = (const float*)d_in[3];
    const float* rel_table = (const float*)d_in[4];
    const int* rel_index = (const int*)d_in[5];
    for (int i = 0; i < n_in; ++i) {
        switch (in_sizes[i]) {
            case 256 * NTOK * DIMX:  x         = (const float*)d_in[i]; break;
            case 64 * NTOK * NTOK:   mask      = (const float*)d_in[i]; break;
            case 3 * DIMX * DIMX:    qkv_w     = (const float*)d_in[i]; break;
            case 3 * DIMX:           qkv_b     = (const float*)d_in[i]; break;
            case 507 * NHEAD:        rel_table = (const float*)d_in[i]; break;
            case NTOK * NTOK:        rel_index = (const int*)d_in[i]; break;
            default: break;
        }
    }
    float* out = (float*)d_out;

    const size_t bias_bytes = (size_t)NHEAD * NTOK * NTOK * sizeof(float); // 921984
    const size_t xb_bytes   = (size_t)BROWS * DIMX * 2;                    // 38535168
    const size_t wb_bytes   = (size_t)NQKV * DIMX * 2;                     // 3538944
    const size_t qkv_bytes  = (size_t)BROWS * NQKV * 2;                    // 115605504
    const size_t total      = bias_bytes + xb_bytes + wb_bytes + qkv_bytes;

    if (ws_size >= total) {
        float* bias_pre = (float*)d_ws;
        short* xb  = (short*)((char*)d_ws + bias_bytes);
        short* wb  = (short*)((char*)d_ws + bias_bytes + xb_bytes);
        short* qkv = (short*)((char*)d_ws + bias_bytes + xb_bytes + wb_bytes);

        int nx4 = BROWS * DIMX / 4;   // 4816896
        int nw4 = NQKV * DIMX / 4;    // 442368
        convert_kernel<<<(nx4 + 255) / 256, 256, 0, stream>>>(x, xb, nx4);
        convert_kernel<<<(nw4 + 255) / 256, 256, 0, stream>>>(qkv_w, wb, nw4);
        int nb = NHEAD * NTOK * NTOK;
        bias_gather_kernel<<<(nb + 255) / 256, 256, 0, stream>>>(rel_table, rel_index, bias_pre);
        gemm_kernel<<<196 * 18, 256, 0, stream>>>(xb, wb, qkv_b, qkv);
        attn_kernel2<<<256 * NHEAD, 256, 0, stream>>>(qkv, mask, bias_pre, out);
    } else {
        float* bias_pre = (ws_size >= bias_bytes) ? (float*)d_ws : nullptr;
        if (bias_pre) {
            int nb = NHEAD * NTOK * NTOK;
            bias_gather_kernel<<<(nb + 255) / 256, 256, 0, stream>>>(rel_table, rel_index, bias_pre);
        }
        attn_fused<<<256 * NHEAD, 256, 0, stream>>>(x, mask, qkv_w, qkv_b,
                                                    bias_pre, rel_table, rel_index, out);
    }
}